// Round 8
// baseline (1104.584 us; speedup 1.0000x reference)
//
#include <hip/hip_runtime.h>
#include <hip/hip_bf16.h>

// ============================================================================
// TransformerChoiceNet forward. Round 8: (1) attention exp back to native
// __expf (r7's exp2f was libm -> ~10 VALU/call, the failed-prediction cause),
// (2) XCD-aware flat attention grid (qc-sharers same XCD, adjacent dispatch),
// (3) VT epilogue packed 8B stores (was 2B scatter).
// B=128 S=512 D=64 H=256 NH=8 HD=32, M=B*S=65536.
// ============================================================================

#define Bb  128
#define Ss  512
#define Hh  256
#define NHh 8
#define Mm  (Bb*Ss)

typedef unsigned short bf16_t;
typedef __attribute__((ext_vector_type(8))) short short8;
typedef __attribute__((ext_vector_type(4))) float f32x4;

__device__ __forceinline__ float bf2f(bf16_t h){
  union { unsigned int u; float f; } v; v.u = ((unsigned int)h)<<16; return v.f;
}
__device__ __forceinline__ bf16_t f2bf(float f){
  union { float f; unsigned int u; } v; v.f = f;
  unsigned int r = (v.u + 0x7fffu + ((v.u>>16)&1u)) >> 16;   // RNE
  return (bf16_t)r;
}
__device__ __forceinline__ unsigned pk_bf16(float a, float b){  // packed RNE cvt
  union { __hip_bfloat162 h; unsigned u; } v;
  v.h = __float22bfloat162_rn(float2{a,b});
  return v.u;
}
__device__ __forceinline__ short8 ld_bf8(const bf16_t* p){   // 16B load
  union { uint4 u; short8 s; } v; v.u = *(const uint4*)p; return v.s;
}
__device__ __forceinline__ void gload16(const bf16_t* g, bf16_t* l){
  __builtin_amdgcn_global_load_lds(
      (const __attribute__((address_space(1))) void*)g,
      (__attribute__((address_space(3))) void*)l, 16, 0, 0);
}
__device__ __forceinline__ float gelu_f(float x){
  float u = 0.7978845608028654f*(x + 0.044715f*x*x*x);
  return 0.5f*x*(1.0f + tanhf(u));
}

// ---------------- weight prep: fp32 W[k][n] -> bf16 Wt[n][k] ------------------
struct PrepDesc { const float* s; unsigned off; int K; };
struct Prep18  { PrepDesc d[18]; };

__global__ __launch_bounds__(256) void k_prep(Prep18 p, bf16_t* __restrict__ arena)
{
  PrepDesc dd = p.d[blockIdx.y];
  int i = blockIdx.x*256 + threadIdx.x;
  if (i < dd.K*256){
    int k = i>>8, n = i&255;
    arena[dd.off + n*dd.K + k] = f2bf(dd.s[i]);
  }
}

// ---------------- LN0 (two gains) + valid mask; bf16 out ----------------------
__global__ __launch_bounds__(256) void k_ln0(const float* __restrict__ src,
    const float* __restrict__ gs, const float* __restrict__ bs,
    const float* __restrict__ gt, const float* __restrict__ bt,
    bf16_t* __restrict__ xs, bf16_t* __restrict__ xt, float* __restrict__ valid)
{
  int row  = blockIdx.x*4 + (threadIdx.x>>6);
  int lane = threadIdx.x & 63;
  float x = src[(size_t)row*64 + lane];
  float s = x;
  #pragma unroll
  for (int o=32;o>0;o>>=1) s += __shfl_xor(s,o);
  float mean = s*(1.0f/64.0f);
  float d = x - mean;
  float ss = d*d;
  #pragma unroll
  for (int o=32;o>0;o>>=1) ss += __shfl_xor(ss,o);
  float r = rsqrtf(ss*(1.0f/64.0f) + 1e-5f);
  float xn = d*r;
  xs[(size_t)row*64+lane] = f2bf(xn*gs[lane] + bs[lane]);
  xt[(size_t)row*64+lane] = f2bf(xn*gt[lane] + bt[lane]);
  if (lane==0) valid[row] = (s != 0.0f) ? 1.0f : 0.0f;
}

// ---------------- MFMA GEMM: block 64m x 256n, BK=64, LDS staged --------------
// OUTM: 0 bf16 C[M,256] (EPI 0/1) | 2 bf16 VT[b][n][s] packed 8B stores |
//       3 LN(Pres+(acc+b)) -> bf16 P | 5 like 3 but dot outW -> fp32 logits.
template<int EPI, int OUTM>
__global__ __launch_bounds__(256,3) void k_gemm(const bf16_t* __restrict__ A,
    const bf16_t* __restrict__ Wt, const float* __restrict__ bias,
    void* __restrict__ Cv, const bf16_t* __restrict__ Pres,
    const float* __restrict__ g, const float* __restrict__ bb,
    const float* __restrict__ oW, const float* __restrict__ obp, int K)
{
  __shared__ bf16_t As[8*512];    // 8 KB
  __shared__ bf16_t Bs[32*512];   // 32 KB
  int t = threadIdx.x, w = t>>6, lane = t&63, l15 = lane&15, quad = lane>>4;
  int m0 = blockIdx.x*64;
  f32x4 z = {0.f,0.f,0.f,0.f};
  f32x4 acc[4][4] = {{z,z,z,z},{z,z,z,z},{z,z,z,z},{z,z,z,z}};

  for (int k0=0; k0<K; k0+=64){
    #pragma unroll
    for (int j=0; j<2; j++){
      int id = 2*w + j; int kc32 = id>>2, mt = id&3;
      gload16(A + (size_t)(m0 + mt*16 + l15)*K + k0 + kc32*32 + quad*8,
              &As[id*512]);
    }
    #pragma unroll
    for (int j=0; j<8; j++){
      int id = 8*w + j; int kc32 = id>>4, gnt = id&15;
      gload16(Wt + (size_t)(gnt*16 + l15)*K + k0 + kc32*32 + quad*8,
              &Bs[id*512]);
    }
    __syncthreads();
    #pragma unroll
    for (int kc=0; kc<2; kc++){
      short8 a[4], b[4];
      #pragma unroll
      for (int mt=0; mt<4; mt++) a[mt] = ld_bf8(&As[(kc*4+mt)*512 + lane*8]);
      #pragma unroll
      for (int nt=0; nt<4; nt++) b[nt] = ld_bf8(&Bs[(kc*16 + w*4 + nt)*512 + lane*8]);
      #pragma unroll
      for (int mt=0; mt<4; mt++)
        #pragma unroll
        for (int nt=0; nt<4; nt++)
          acc[mt][nt] = __builtin_amdgcn_mfma_f32_16x16x32_bf16(a[mt], b[nt], acc[mt][nt], 0,0,0);
    }
    __syncthreads();
  }

  float bv[4];
  #pragma unroll
  for (int nt=0; nt<4; nt++) bv[nt] = bias[w*64 + nt*16 + l15];

  if (OUTM==0){
    #pragma unroll
    for (int mt=0; mt<4; mt++)
      #pragma unroll
      for (int nt=0; nt<4; nt++)
        #pragma unroll
        for (int r=0; r<4; r++){
          int row = m0 + mt*16 + quad*4 + r;
          int col = w*64 + nt*16 + l15;
          float v = acc[mt][nt][r] + bv[nt];
          if (EPI==1) v = gelu_f(v);
          ((bf16_t*)Cv)[(size_t)row*256 + col] = f2bf(v);
        }
  } else if (OUTM==2){
    // VT[b][n][s]: 4 consecutive r = 4 consecutive s -> one 8B packed store
    #pragma unroll
    for (int mt=0; mt<4; mt++)
      #pragma unroll
      for (int nt=0; nt<4; nt++){
        int m = m0 + mt*16 + quad*4;
        int col = w*64 + nt*16 + l15;
        uint2 pk = { pk_bf16(acc[mt][nt][0]+bv[nt], acc[mt][nt][1]+bv[nt]),
                     pk_bf16(acc[mt][nt][2]+bv[nt], acc[mt][nt][3]+bv[nt]) };
        *(uint2*)&((bf16_t*)Cv)[((size_t)((m>>9)*256 + col))*512 + (m&511)] = pk;
      }
  } else {
    float* RedS = (float*)As;          // [64][4]
    float* RedQ = RedS + 256;          // [64][4]
    #pragma unroll
    for (int mt=0; mt<4; mt++)
      #pragma unroll
      for (int r=0; r<4; r++){
        int row = m0 + mt*16 + quad*4 + r;
        const bf16_t* pr = Pres + (size_t)row*256;
        float s = 0.f, q = 0.f;
        #pragma unroll
        for (int nt=0; nt<4; nt++){
          float v = acc[mt][nt][r] + bv[nt] + bf2f(pr[w*64 + nt*16 + l15]);
          s += v; q += v*v;
        }
        s += __shfl_xor(s,1); s += __shfl_xor(s,2);
        s += __shfl_xor(s,4); s += __shfl_xor(s,8);
        q += __shfl_xor(q,1); q += __shfl_xor(q,2);
        q += __shfl_xor(q,4); q += __shfl_xor(q,8);
        if (l15==0){
          int rr = mt*16 + quad*4 + r;
          RedS[rr*4 + w] = s; RedQ[rr*4 + w] = q;
        }
      }
    __syncthreads();

    float gv[4], bbv[4], wv[4];
    #pragma unroll
    for (int nt=0; nt<4; nt++){ gv[nt] = g[w*64+nt*16+l15]; bbv[nt] = bb[w*64+nt*16+l15]; }
    if (OUTM==5)
      #pragma unroll
      for (int nt=0; nt<4; nt++) wv[nt] = oW[w*64+nt*16+l15];

    float s2p[4][4];
    #pragma unroll
    for (int mt=0; mt<4; mt++)
      #pragma unroll
      for (int r=0; r<4; r++){
        int rr = mt*16 + quad*4 + r;
        int row = m0 + rr;
        float S = RedS[rr*4+0]+RedS[rr*4+1]+RedS[rr*4+2]+RedS[rr*4+3];
        float Q = RedQ[rr*4+0]+RedQ[rr*4+1]+RedQ[rr*4+2]+RedQ[rr*4+3];
        float mean = S*(1.0f/256.0f);
        float var  = Q*(1.0f/256.0f) - mean*mean;
        float rstd = rsqrtf(var + 1e-5f);
        const bf16_t* pr = Pres + (size_t)row*256;
        if (OUTM==3){
          bf16_t* po = (bf16_t*)Cv + (size_t)row*256;
          #pragma unroll
          for (int nt=0; nt<4; nt++){
            float v = acc[mt][nt][r] + bv[nt] + bf2f(pr[w*64 + nt*16 + l15]);
            po[w*64 + nt*16 + l15] = f2bf((v-mean)*rstd*gv[nt] + bbv[nt]);
          }
        } else {
          float s2 = 0.f;
          #pragma unroll
          for (int nt=0; nt<4; nt++){
            float v = acc[mt][nt][r] + bv[nt] + bf2f(pr[w*64 + nt*16 + l15]);
            s2 += ((v-mean)*rstd*gv[nt] + bbv[nt]) * wv[nt];
          }
          s2 += __shfl_xor(s2,1); s2 += __shfl_xor(s2,2);
          s2 += __shfl_xor(s2,4); s2 += __shfl_xor(s2,8);
          s2p[mt][r] = s2;
        }
      }
    if (OUTM==5){
      __syncthreads();
      #pragma unroll
      for (int mt=0; mt<4; mt++)
        #pragma unroll
        for (int r=0; r<4; r++)
          if (l15==0) RedS[(mt*16 + quad*4 + r)*4 + w] = s2p[mt][r];
      __syncthreads();
      if (w==0){
        float S = RedS[lane*4+0]+RedS[lane*4+1]+RedS[lane*4+2]+RedS[lane*4+3];
        ((float*)Cv)[m0 + lane] = S + obp[0];
      }
    }
  }
}

// ---------------- MFMA attention: transposed QK^T, native exp, XCD swizzle ----
// Flat grid 4096: h=bid&7, qc=(bid>>3)&3, b=bid>>5 -> the 4 qc-sharers of one
// (b,h) K/V slice land on the same XCD (%8 round-robin) adjacent in time.
// S^T = mfma(aK,aQ): lane holds S[q=l15][key=ktile*16+quad*4+r].
__global__ __launch_bounds__(256) void k_attn(const bf16_t* __restrict__ Qm,
    const bf16_t* __restrict__ Km, const bf16_t* __restrict__ VT,
    const float* __restrict__ valid, bf16_t* __restrict__ AO)
{
  __shared__ bf16_t Pbuf[4][2][16][40];
  __shared__ float  Smask[512];       // 0 or -1e10
  int t = threadIdx.x, wave = t>>6, lane = t&63, l15 = lane&15, quad = lane>>4;
  int bid = blockIdx.x;
  int h = bid & 7, qc = (bid>>3) & 3, b = bid>>5;
  int q0 = qc*128;
  const float scale = 0.17677669529663687f;   // 1/sqrt(32)

  Smask[t]     = (valid[b*Ss + t      ] != 0.f) ? 0.f : -1.0e10f;
  Smask[t+256] = (valid[b*Ss + t + 256] != 0.f) ? 0.f : -1.0e10f;
  __syncthreads();

  short8 aQ0 = ld_bf8(Qm + (size_t)(b*Ss + q0 + (wave*2  )*16 + l15)*256 + h*32 + quad*8);
  short8 aQ1 = ld_bf8(Qm + (size_t)(b*Ss + q0 + (wave*2+1)*16 + l15)*256 + h*32 + quad*8);
  const bf16_t* Vb = VT + ((size_t)b*256 + h*32)*512;

  f32x4 z = {0.f,0.f,0.f,0.f};
  f32x4 O0[2] = {z,z}, O1[2] = {z,z};
  float ls0 = 0.f, ls1 = 0.f;    // per-lane partial rowsum for q=l15

  for (int kt2=0; kt2<16; kt2++){
    #pragma unroll
    for (int half=0; half<2; half++){
      int ktile = kt2*2 + half;
      short8 aK = ld_bf8(Km + (size_t)(b*Ss + ktile*16 + l15)*256 + h*32 + quad*8);
      f32x4 s0 = __builtin_amdgcn_mfma_f32_16x16x32_bf16(aK, aQ0, z, 0,0,0);
      f32x4 s1 = __builtin_amdgcn_mfma_f32_16x16x32_bf16(aK, aQ1, z, 0,0,0);
      float4 mb = *(const float4*)&Smask[ktile*16 + quad*4];
      float p00 = __expf(fmaf(s0[0],scale, mb.x));   // native v_exp; masked -> 0
      float p01 = __expf(fmaf(s0[1],scale, mb.y));
      float p02 = __expf(fmaf(s0[2],scale, mb.z));
      float p03 = __expf(fmaf(s0[3],scale, mb.w));
      float p10 = __expf(fmaf(s1[0],scale, mb.x));
      float p11 = __expf(fmaf(s1[1],scale, mb.y));
      float p12 = __expf(fmaf(s1[2],scale, mb.z));
      float p13 = __expf(fmaf(s1[3],scale, mb.w));
      ls0 += (p00+p01)+(p02+p03);
      ls1 += (p10+p11)+(p12+p13);
      uint2 w0 = { pk_bf16(p00,p01), pk_bf16(p02,p03) };
      uint2 w1 = { pk_bf16(p10,p11), pk_bf16(p12,p13) };
      *(uint2*)&Pbuf[wave][0][l15][half*16 + quad*4] = w0;
      *(uint2*)&Pbuf[wave][1][l15][half*16 + quad*4] = w1;
    }
    short8 aP0 = ld_bf8(&Pbuf[wave][0][l15][quad*8]);   // A[m=q][k=key]
    short8 aP1 = ld_bf8(&Pbuf[wave][1][l15][quad*8]);
    #pragma unroll
    for (int nt=0; nt<2; nt++){
      short8 bV = ld_bf8(Vb + (size_t)(nt*16+l15)*512 + kt2*32 + quad*8);
      O0[nt] = __builtin_amdgcn_mfma_f32_16x16x32_bf16(aP0, bV, O0[nt], 0,0,0);
      O1[nt] = __builtin_amdgcn_mfma_f32_16x16x32_bf16(aP1, bV, O1[nt], 0,0,0);
    }
  }

  ls0 += __shfl_xor(ls0,16); ls0 += __shfl_xor(ls0,32);
  ls1 += __shfl_xor(ls1,16); ls1 += __shfl_xor(ls1,32);
  float linv0 = (ls0 > 0.f) ? 1.0f/ls0 : 0.f;
  float linv1 = (ls1 > 0.f) ? 1.0f/ls1 : 0.f;
  float i0[4], i1[4];
  #pragma unroll
  for (int r=0; r<4; r++){
    i0[r] = __shfl(linv0, quad*4 + r);
    i1[r] = __shfl(linv1, quad*4 + r);
  }
  size_t r0 = (size_t)(b*Ss + q0 + (wave*2  )*16);
  size_t r1 = (size_t)(b*Ss + q0 + (wave*2+1)*16);
  #pragma unroll
  for (int nt=0; nt<2; nt++)
    #pragma unroll
    for (int r=0; r<4; r++){
      AO[(r0 + quad*4 + r)*256 + h*32 + nt*16 + l15] = f2bf(O0[nt][r]*i0[r]);
      AO[(r1 + quad*4 + r)*256 + h*32 + nt*16 + l15] = f2bf(O1[nt][r]*i1[r]);
    }
}

// ---------------- final: p = exp(logits)*valid, normalize per batch -----------
__global__ __launch_bounds__(256) void k_final(const float* __restrict__ L,
    const float* __restrict__ valid, float* __restrict__ out)
{
  __shared__ float wsum[4];
  int b = blockIdx.x, t = threadIdx.x;
  float e0 = __expf(L[b*Ss + t      ]) * valid[b*Ss + t      ];
  float e1 = __expf(L[b*Ss + 256 + t]) * valid[b*Ss + 256 + t];
  float s = e0 + e1;
  #pragma unroll
  for (int o=32;o>0;o>>=1) s += __shfl_xor(s,o);
  if ((t&63)==0) wsum[t>>6] = s;
  __syncthreads();
  float tot = wsum[0]+wsum[1]+wsum[2]+wsum[3];
  out[b*Ss + t      ] = e0/tot;
  out[b*Ss + 256 + t] = e1/tot;
}

// ============================================================================
extern "C" void kernel_launch(void* const* d_in, const int* in_sizes, int n_in,
                              void* d_out, int out_size, void* d_ws, size_t ws_size,
                              hipStream_t stream)
{
  #define F(i) ((const float*)d_in[(i)])
  bool sig = (in_sizes[33] == 256);   // signature order vs dict order
  const float* d_eqW  = F(sig?35:33); const float* d_eqb  = F(sig?36:34);
  const float* d_ekW  = F(sig?37:35); const float* d_ekb  = F(sig?38:36);
  const float* d_evW  = F(sig?39:37); const float* d_evb  = F(sig?40:38);
  const float* d_eoW  = F(sig?41:39); const float* d_eob  = F(sig?42:40);
  const float* d_ln1g = F(sig?33:41); const float* d_ln1b = F(sig?34:42);

  // ---- workspace (~163 MiB) ----
  char* w = (char*)d_ws;
  bf16_t* P0 = (bf16_t*)w; w += (size_t)Mm*Hh*2;   // 32 MiB residual (enc)
  bf16_t* P1 = (bf16_t*)w; w += (size_t)Mm*Hh*2;   // 32 MiB residual (dec)
  bf16_t* H0 = (bf16_t*)w; w += (size_t)Mm*Hh*2;   // 32 MiB Q / AO / gelu
  bf16_t* H1 = (bf16_t*)w;                          // 32 MiB K / xs alias
  bf16_t* xs = (bf16_t*)w; w += (size_t)Mm*Hh*2;
  bf16_t* H2 = (bf16_t*)w;                          // 32 MiB VT / xt alias
  bf16_t* xt = (bf16_t*)w; w += (size_t)Mm*Hh*2;
  bf16_t* Wa = (bf16_t*)w; w += (size_t)(2*16384 + 16*65536)*2;  // 2.1 MiB
  float*  valid  = (float*)w; w += (size_t)Mm*4;
  float*  logits = (float*)w; w += (size_t)Mm*4;
  float* out = (float*)d_out;

  unsigned o_sem = 0, o_tem = 16384;
  unsigned o_w[16]; for (int i=0;i<16;i++) o_w[i] = 32768 + i*65536u;
  Prep18 pp;
  const float* srcs[18] = { F(5), F(7), F(9), F(11), F(13), F(15), F(19), F(21),
                            F(25), F(27), F(29), F(31), d_eqW, d_ekW, d_evW, d_eoW,
                            F(45), F(47) };
  unsigned offs[18] = { o_sem, o_tem, o_w[0],o_w[1],o_w[2],o_w[3],o_w[4],o_w[5],
                        o_w[6],o_w[7],o_w[8],o_w[9],o_w[10],o_w[11],o_w[12],o_w[13],
                        o_w[14],o_w[15] };
  for (int i=0;i<18;i++){ pp.d[i].s = srcs[i]; pp.d[i].off = offs[i]; pp.d[i].K = (i<2)?64:256; }

  dim3 blk(256);
  dim3 gLN(Mm/4);
  dim3 gG(Mm/64);
  dim3 gA(NHh*Bb*4);     // flat; kernel decodes h=bid&7, qc=(bid>>3)&3, b=bid>>5
  dim3 gP(256, 18);
  const float* NF = nullptr; const bf16_t* NB = nullptr;

  k_prep<<<gP, blk, 0, stream>>>(pp, Wa);
  k_ln0<<<gLN, blk, 0, stream>>>(F(0), F(1),F(2), F(3),F(4), xs, xt, valid);

  k_gemm<0,0><<<gG, blk, 0, stream>>>(xs, Wa+o_sem, F(6), P0, NB,NF,NF,NF,NF, 64);
  k_gemm<0,0><<<gG, blk, 0, stream>>>(xt, Wa+o_tem, F(8), P1, NB,NF,NF,NF,NF, 64);

  // ---- encoder ----
  k_gemm<0,0><<<gG, blk, 0, stream>>>(P0, Wa+o_w[0], F(10), H0, NB,NF,NF,NF,NF, 256);
  k_gemm<0,0><<<gG, blk, 0, stream>>>(P0, Wa+o_w[1], F(12), H1, NB,NF,NF,NF,NF, 256);
  k_gemm<0,2><<<gG, blk, 0, stream>>>(P0, Wa+o_w[2], F(14), H2, NB,NF,NF,NF,NF, 256);
  k_attn<<<gA, blk, 0, stream>>>(H0, H1, H2, valid, H0);
  k_gemm<0,3><<<gG, blk, 0, stream>>>(H0, Wa+o_w[3], F(16), P0, P0, F(17),F(18), NF,NF, 256);
  k_gemm<1,0><<<gG, blk, 0, stream>>>(P0, Wa+o_w[4], F(20), H0, NB,NF,NF,NF,NF, 256);
  k_gemm<0,3><<<gG, blk, 0, stream>>>(H0, Wa+o_w[5], F(22), P0, P0, F(23),F(24), NF,NF, 256);

  // ---- decoder self-attention ----
  k_gemm<0,0><<<gG, blk, 0, stream>>>(P1, Wa+o_w[6], F(26), H0, NB,NF,NF,NF,NF, 256);
  k_gemm<0,0><<<gG, blk, 0, stream>>>(P1, Wa+o_w[7], F(28), H1, NB,NF,NF,NF,NF, 256);
  k_gemm<0,2><<<gG, blk, 0, stream>>>(P1, Wa+o_w[8], F(30), H2, NB,NF,NF,NF,NF, 256);
  k_attn<<<gA, blk, 0, stream>>>(H0, H1, H2, valid, H0);
  k_gemm<0,3><<<gG, blk, 0, stream>>>(H0, Wa+o_w[9], F(32), P1, P1, d_ln1g,d_ln1b, NF,NF, 256);

  // ---- decoder cross-attention ----
  k_gemm<0,0><<<gG, blk, 0, stream>>>(P1, Wa+o_w[10], d_eqb, H0, NB,NF,NF,NF,NF, 256);
  k_gemm<0,0><<<gG, blk, 0, stream>>>(P0, Wa+o_w[11], d_ekb, H1, NB,NF,NF,NF,NF, 256);
  k_gemm<0,2><<<gG, blk, 0, stream>>>(P0, Wa+o_w[12], d_evb, H2, NB,NF,NF,NF,NF, 256);
  k_attn<<<gA, blk, 0, stream>>>(H0, H1, H2, valid, H0);
  k_gemm<0,3><<<gG, blk, 0, stream>>>(H0, Wa+o_w[13], d_eob, P1, P1, F(43),F(44), NF,NF, 256);

  // ---- decoder FFN + fused ln3 + logits ----
  k_gemm<1,0><<<gG, blk, 0, stream>>>(P1, Wa+o_w[14], F(46), H0, NB,NF,NF,NF,NF, 256);
  k_gemm<0,5><<<gG, blk, 0, stream>>>(H0, Wa+o_w[15], F(48), logits, P1, F(49),F(50), F(51),F(52), 256);

  k_final<<<dim3(Bb), blk, 0, stream>>>(logits, valid, out);
  #undef F
}

// Round 9
// 1071.645 us; speedup vs baseline: 1.0307x; 1.0307x over previous
//
#include <hip/hip_runtime.h>
#include <hip/hip_bf16.h>

// ============================================================================
// TransformerChoiceNet forward. Round 9: attention K-loop software pipeline —
// 2-slot Pbuf; iteration kt2: prefetch K/V(kt2+1), PV-MFMA(kt2), QK+exp+pack
// (kt2+1). Grid back to r7's 3D (measured faster than r8 XCD swizzle).
// Keeps r8's __expf+fma (cheap native exp) and VT packed stores.
// B=128 S=512 D=64 H=256 NH=8 HD=32, M=B*S=65536.
// ============================================================================

#define Bb  128
#define Ss  512
#define Hh  256
#define NHh 8
#define Mm  (Bb*Ss)

typedef unsigned short bf16_t;
typedef __attribute__((ext_vector_type(8))) short short8;
typedef __attribute__((ext_vector_type(4))) float f32x4;

__device__ __forceinline__ float bf2f(bf16_t h){
  union { unsigned int u; float f; } v; v.u = ((unsigned int)h)<<16; return v.f;
}
__device__ __forceinline__ bf16_t f2bf(float f){
  union { float f; unsigned int u; } v; v.f = f;
  unsigned int r = (v.u + 0x7fffu + ((v.u>>16)&1u)) >> 16;   // RNE
  return (bf16_t)r;
}
__device__ __forceinline__ unsigned pk_bf16(float a, float b){  // packed RNE cvt
  union { __hip_bfloat162 h; unsigned u; } v;
  v.h = __float22bfloat162_rn(float2{a,b});
  return v.u;
}
__device__ __forceinline__ short8 ld_bf8(const bf16_t* p){   // 16B load
  union { uint4 u; short8 s; } v; v.u = *(const uint4*)p; return v.s;
}
__device__ __forceinline__ void gload16(const bf16_t* g, bf16_t* l){
  __builtin_amdgcn_global_load_lds(
      (const __attribute__((address_space(1))) void*)g,
      (__attribute__((address_space(3))) void*)l, 16, 0, 0);
}
__device__ __forceinline__ float gelu_f(float x){
  float u = 0.7978845608028654f*(x + 0.044715f*x*x*x);
  return 0.5f*x*(1.0f + tanhf(u));
}

// ---------------- weight prep: fp32 W[k][n] -> bf16 Wt[n][k] ------------------
struct PrepDesc { const float* s; unsigned off; int K; };
struct Prep18  { PrepDesc d[18]; };

__global__ __launch_bounds__(256) void k_prep(Prep18 p, bf16_t* __restrict__ arena)
{
  PrepDesc dd = p.d[blockIdx.y];
  int i = blockIdx.x*256 + threadIdx.x;
  if (i < dd.K*256){
    int k = i>>8, n = i&255;
    arena[dd.off + n*dd.K + k] = f2bf(dd.s[i]);
  }
}

// ---------------- LN0 (two gains) + valid mask; bf16 out ----------------------
__global__ __launch_bounds__(256) void k_ln0(const float* __restrict__ src,
    const float* __restrict__ gs, const float* __restrict__ bs,
    const float* __restrict__ gt, const float* __restrict__ bt,
    bf16_t* __restrict__ xs, bf16_t* __restrict__ xt, float* __restrict__ valid)
{
  int row  = blockIdx.x*4 + (threadIdx.x>>6);
  int lane = threadIdx.x & 63;
  float x = src[(size_t)row*64 + lane];
  float s = x;
  #pragma unroll
  for (int o=32;o>0;o>>=1) s += __shfl_xor(s,o);
  float mean = s*(1.0f/64.0f);
  float d = x - mean;
  float ss = d*d;
  #pragma unroll
  for (int o=32;o>0;o>>=1) ss += __shfl_xor(ss,o);
  float r = rsqrtf(ss*(1.0f/64.0f) + 1e-5f);
  float xn = d*r;
  xs[(size_t)row*64+lane] = f2bf(xn*gs[lane] + bs[lane]);
  xt[(size_t)row*64+lane] = f2bf(xn*gt[lane] + bt[lane]);
  if (lane==0) valid[row] = (s != 0.0f) ? 1.0f : 0.0f;
}

// ---------------- MFMA GEMM: block 64m x 256n, BK=64, LDS staged --------------
// OUTM: 0 bf16 C[M,256] (EPI 0/1) | 2 bf16 VT[b][n][s] packed 8B stores |
//       3 LN(Pres+(acc+b)) -> bf16 P | 5 like 3 but dot outW -> fp32 logits.
template<int EPI, int OUTM>
__global__ __launch_bounds__(256,3) void k_gemm(const bf16_t* __restrict__ A,
    const bf16_t* __restrict__ Wt, const float* __restrict__ bias,
    void* __restrict__ Cv, const bf16_t* __restrict__ Pres,
    const float* __restrict__ g, const float* __restrict__ bb,
    const float* __restrict__ oW, const float* __restrict__ obp, int K)
{
  __shared__ bf16_t As[8*512];    // 8 KB
  __shared__ bf16_t Bs[32*512];   // 32 KB
  int t = threadIdx.x, w = t>>6, lane = t&63, l15 = lane&15, quad = lane>>4;
  int m0 = blockIdx.x*64;
  f32x4 z = {0.f,0.f,0.f,0.f};
  f32x4 acc[4][4] = {{z,z,z,z},{z,z,z,z},{z,z,z,z},{z,z,z,z}};

  for (int k0=0; k0<K; k0+=64){
    #pragma unroll
    for (int j=0; j<2; j++){
      int id = 2*w + j; int kc32 = id>>2, mt = id&3;
      gload16(A + (size_t)(m0 + mt*16 + l15)*K + k0 + kc32*32 + quad*8,
              &As[id*512]);
    }
    #pragma unroll
    for (int j=0; j<8; j++){
      int id = 8*w + j; int kc32 = id>>4, gnt = id&15;
      gload16(Wt + (size_t)(gnt*16 + l15)*K + k0 + kc32*32 + quad*8,
              &Bs[id*512]);
    }
    __syncthreads();
    #pragma unroll
    for (int kc=0; kc<2; kc++){
      short8 a[4], b[4];
      #pragma unroll
      for (int mt=0; mt<4; mt++) a[mt] = ld_bf8(&As[(kc*4+mt)*512 + lane*8]);
      #pragma unroll
      for (int nt=0; nt<4; nt++) b[nt] = ld_bf8(&Bs[(kc*16 + w*4 + nt)*512 + lane*8]);
      #pragma unroll
      for (int mt=0; mt<4; mt++)
        #pragma unroll
        for (int nt=0; nt<4; nt++)
          acc[mt][nt] = __builtin_amdgcn_mfma_f32_16x16x32_bf16(a[mt], b[nt], acc[mt][nt], 0,0,0);
    }
    __syncthreads();
  }

  float bv[4];
  #pragma unroll
  for (int nt=0; nt<4; nt++) bv[nt] = bias[w*64 + nt*16 + l15];

  if (OUTM==0){
    #pragma unroll
    for (int mt=0; mt<4; mt++)
      #pragma unroll
      for (int nt=0; nt<4; nt++)
        #pragma unroll
        for (int r=0; r<4; r++){
          int row = m0 + mt*16 + quad*4 + r;
          int col = w*64 + nt*16 + l15;
          float v = acc[mt][nt][r] + bv[nt];
          if (EPI==1) v = gelu_f(v);
          ((bf16_t*)Cv)[(size_t)row*256 + col] = f2bf(v);
        }
  } else if (OUTM==2){
    // VT[b][n][s]: 4 consecutive r = 4 consecutive s -> one 8B packed store
    #pragma unroll
    for (int mt=0; mt<4; mt++)
      #pragma unroll
      for (int nt=0; nt<4; nt++){
        int m = m0 + mt*16 + quad*4;
        int col = w*64 + nt*16 + l15;
        uint2 pk = { pk_bf16(acc[mt][nt][0]+bv[nt], acc[mt][nt][1]+bv[nt]),
                     pk_bf16(acc[mt][nt][2]+bv[nt], acc[mt][nt][3]+bv[nt]) };
        *(uint2*)&((bf16_t*)Cv)[((size_t)((m>>9)*256 + col))*512 + (m&511)] = pk;
      }
  } else {
    float* RedS = (float*)As;          // [64][4]
    float* RedQ = RedS + 256;          // [64][4]
    #pragma unroll
    for (int mt=0; mt<4; mt++)
      #pragma unroll
      for (int r=0; r<4; r++){
        int row = m0 + mt*16 + quad*4 + r;
        const bf16_t* pr = Pres + (size_t)row*256;
        float s = 0.f, q = 0.f;
        #pragma unroll
        for (int nt=0; nt<4; nt++){
          float v = acc[mt][nt][r] + bv[nt] + bf2f(pr[w*64 + nt*16 + l15]);
          s += v; q += v*v;
        }
        s += __shfl_xor(s,1); s += __shfl_xor(s,2);
        s += __shfl_xor(s,4); s += __shfl_xor(s,8);
        q += __shfl_xor(q,1); q += __shfl_xor(q,2);
        q += __shfl_xor(q,4); q += __shfl_xor(q,8);
        if (l15==0){
          int rr = mt*16 + quad*4 + r;
          RedS[rr*4 + w] = s; RedQ[rr*4 + w] = q;
        }
      }
    __syncthreads();

    float gv[4], bbv[4], wv[4];
    #pragma unroll
    for (int nt=0; nt<4; nt++){ gv[nt] = g[w*64+nt*16+l15]; bbv[nt] = bb[w*64+nt*16+l15]; }
    if (OUTM==5)
      #pragma unroll
      for (int nt=0; nt<4; nt++) wv[nt] = oW[w*64+nt*16+l15];

    float s2p[4][4];
    #pragma unroll
    for (int mt=0; mt<4; mt++)
      #pragma unroll
      for (int r=0; r<4; r++){
        int rr = mt*16 + quad*4 + r;
        int row = m0 + rr;
        float S = RedS[rr*4+0]+RedS[rr*4+1]+RedS[rr*4+2]+RedS[rr*4+3];
        float Q = RedQ[rr*4+0]+RedQ[rr*4+1]+RedQ[rr*4+2]+RedQ[rr*4+3];
        float mean = S*(1.0f/256.0f);
        float var  = Q*(1.0f/256.0f) - mean*mean;
        float rstd = rsqrtf(var + 1e-5f);
        const bf16_t* pr = Pres + (size_t)row*256;
        if (OUTM==3){
          bf16_t* po = (bf16_t*)Cv + (size_t)row*256;
          #pragma unroll
          for (int nt=0; nt<4; nt++){
            float v = acc[mt][nt][r] + bv[nt] + bf2f(pr[w*64 + nt*16 + l15]);
            po[w*64 + nt*16 + l15] = f2bf((v-mean)*rstd*gv[nt] + bbv[nt]);
          }
        } else {
          float s2 = 0.f;
          #pragma unroll
          for (int nt=0; nt<4; nt++){
            float v = acc[mt][nt][r] + bv[nt] + bf2f(pr[w*64 + nt*16 + l15]);
            s2 += ((v-mean)*rstd*gv[nt] + bbv[nt]) * wv[nt];
          }
          s2 += __shfl_xor(s2,1); s2 += __shfl_xor(s2,2);
          s2 += __shfl_xor(s2,4); s2 += __shfl_xor(s2,8);
          s2p[mt][r] = s2;
        }
      }
    if (OUTM==5){
      __syncthreads();
      #pragma unroll
      for (int mt=0; mt<4; mt++)
        #pragma unroll
        for (int r=0; r<4; r++)
          if (l15==0) RedS[(mt*16 + quad*4 + r)*4 + w] = s2p[mt][r];
      __syncthreads();
      if (w==0){
        float S = RedS[lane*4+0]+RedS[lane*4+1]+RedS[lane*4+2]+RedS[lane*4+3];
        ((float*)Cv)[m0 + lane] = S + obp[0];
      }
    }
  }
}

// ---------------- MFMA attention: pipelined transposed QK^T -------------------
// Grid (h, b, qc). Wave = 2 q-tiles. 2-slot Pbuf pipeline: iter kt2 prefetches
// K/V(kt2+1), PV-MFMA(kt2) from slot kt2&1, QK+exp+pack(kt2+1) into other slot.
// S^T = mfma(aK,aQ): lane holds S[q=l15][key=ktile*16+quad*4+r].
__global__ __launch_bounds__(256) void k_attn(const bf16_t* __restrict__ Qm,
    const bf16_t* __restrict__ Km, const bf16_t* __restrict__ VT,
    const float* __restrict__ valid, bf16_t* __restrict__ AO)
{
  __shared__ bf16_t Pbuf[4][2][2][16][40];   // [wave][qtile][slot][q][key] 20 KB
  __shared__ float  Smask[512];              // 0 or -1e10
  int t = threadIdx.x, wave = t>>6, lane = t&63, l15 = lane&15, quad = lane>>4;
  int h = blockIdx.x, b = blockIdx.y, qc = blockIdx.z;
  int q0 = qc*128;
  const float scale = 0.17677669529663687f;   // 1/sqrt(32)

  Smask[t]     = (valid[b*Ss + t      ] != 0.f) ? 0.f : -1.0e10f;
  Smask[t+256] = (valid[b*Ss + t + 256] != 0.f) ? 0.f : -1.0e10f;
  __syncthreads();

  short8 aQ0 = ld_bf8(Qm + (size_t)(b*Ss + q0 + (wave*2  )*16 + l15)*256 + h*32 + quad*8);
  short8 aQ1 = ld_bf8(Qm + (size_t)(b*Ss + q0 + (wave*2+1)*16 + l15)*256 + h*32 + quad*8);
  const bf16_t* Kb = Km + (size_t)(b*Ss)*256 + h*32;          // + (key)*256
  const bf16_t* Vb = VT + ((size_t)b*256 + h*32)*512;         // + (d)*512 + key

  f32x4 z = {0.f,0.f,0.f,0.f};
  f32x4 O0[2] = {z,z}, O1[2] = {z,z};
  float ls0 = 0.f, ls1 = 0.f;

  // QK + exp + pack for tile kt2n into slot s, given preloaded K frag pair
  auto process = [&](int kt2n, int s, short8 K0, short8 K1){
    #pragma unroll
    for (int half=0; half<2; half++){
      short8 aK = half ? K1 : K0;
      int ktile = kt2n*2 + half;
      f32x4 s0 = __builtin_amdgcn_mfma_f32_16x16x32_bf16(aK, aQ0, z, 0,0,0);
      f32x4 s1 = __builtin_amdgcn_mfma_f32_16x16x32_bf16(aK, aQ1, z, 0,0,0);
      float4 mb = *(const float4*)&Smask[ktile*16 + quad*4];
      float p00 = __expf(fmaf(s0[0],scale, mb.x));
      float p01 = __expf(fmaf(s0[1],scale, mb.y));
      float p02 = __expf(fmaf(s0[2],scale, mb.z));
      float p03 = __expf(fmaf(s0[3],scale, mb.w));
      float p10 = __expf(fmaf(s1[0],scale, mb.x));
      float p11 = __expf(fmaf(s1[1],scale, mb.y));
      float p12 = __expf(fmaf(s1[2],scale, mb.z));
      float p13 = __expf(fmaf(s1[3],scale, mb.w));
      ls0 += (p00+p01)+(p02+p03);
      ls1 += (p10+p11)+(p12+p13);
      uint2 w0 = { pk_bf16(p00,p01), pk_bf16(p02,p03) };
      uint2 w1 = { pk_bf16(p10,p11), pk_bf16(p12,p13) };
      *(uint2*)&Pbuf[wave][0][s][l15][half*16 + quad*4] = w0;
      *(uint2*)&Pbuf[wave][1][s][l15][half*16 + quad*4] = w1;
    }
  };

  // prologue: K/V for tile 0; stage tile 0 into slot 0
  short8 cK0 = ld_bf8(Kb + (size_t)(l15     )*256 + quad*8);
  short8 cK1 = ld_bf8(Kb + (size_t)(16 + l15)*256 + quad*8);
  short8 cV0 = ld_bf8(Vb + (size_t)(l15     )*512 + quad*8);
  short8 cV1 = ld_bf8(Vb + (size_t)(16 + l15)*512 + quad*8);
  process(0, 0, cK0, cK1);

  #pragma unroll 2
  for (int kt2=0; kt2<16; kt2++){
    int nxt = kt2 + 1;
    short8 nK0, nK1, nV0, nV1;
    if (nxt < 16){                              // prefetch next tile's K and V
      nK0 = ld_bf8(Kb + (size_t)((nxt*2  )*16 + l15)*256 + quad*8);
      nK1 = ld_bf8(Kb + (size_t)((nxt*2+1)*16 + l15)*256 + quad*8);
      nV0 = ld_bf8(Vb + (size_t)(l15     )*512 + nxt*32 + quad*8);
      nV1 = ld_bf8(Vb + (size_t)(16 + l15)*512 + nxt*32 + quad*8);
    }
    int s = kt2 & 1;
    short8 aP0 = ld_bf8(&Pbuf[wave][0][s][l15][quad*8]);
    short8 aP1 = ld_bf8(&Pbuf[wave][1][s][l15][quad*8]);
    O0[0] = __builtin_amdgcn_mfma_f32_16x16x32_bf16(aP0, cV0, O0[0], 0,0,0);
    O0[1] = __builtin_amdgcn_mfma_f32_16x16x32_bf16(aP0, cV1, O0[1], 0,0,0);
    O1[0] = __builtin_amdgcn_mfma_f32_16x16x32_bf16(aP1, cV0, O1[0], 0,0,0);
    O1[1] = __builtin_amdgcn_mfma_f32_16x16x32_bf16(aP1, cV1, O1[1], 0,0,0);
    if (nxt < 16){
      process(nxt, nxt & 1, nK0, nK1);          // overlaps PV/mem of this iter
      cV0 = nV0; cV1 = nV1;
    }
  }

  ls0 += __shfl_xor(ls0,16); ls0 += __shfl_xor(ls0,32);
  ls1 += __shfl_xor(ls1,16); ls1 += __shfl_xor(ls1,32);
  float linv0 = (ls0 > 0.f) ? 1.0f/ls0 : 0.f;
  float linv1 = (ls1 > 0.f) ? 1.0f/ls1 : 0.f;
  float i0[4], i1[4];
  #pragma unroll
  for (int r=0; r<4; r++){
    i0[r] = __shfl(linv0, quad*4 + r);
    i1[r] = __shfl(linv1, quad*4 + r);
  }
  size_t r0 = (size_t)(b*Ss + q0 + (wave*2  )*16);
  size_t r1 = (size_t)(b*Ss + q0 + (wave*2+1)*16);
  #pragma unroll
  for (int nt=0; nt<2; nt++)
    #pragma unroll
    for (int r=0; r<4; r++){
      AO[(r0 + quad*4 + r)*256 + h*32 + nt*16 + l15] = f2bf(O0[nt][r]*i0[r]);
      AO[(r1 + quad*4 + r)*256 + h*32 + nt*16 + l15] = f2bf(O1[nt][r]*i1[r]);
    }
}

// ---------------- final: p = exp(logits)*valid, normalize per batch -----------
__global__ __launch_bounds__(256) void k_final(const float* __restrict__ L,
    const float* __restrict__ valid, float* __restrict__ out)
{
  __shared__ float wsum[4];
  int b = blockIdx.x, t = threadIdx.x;
  float e0 = __expf(L[b*Ss + t      ]) * valid[b*Ss + t      ];
  float e1 = __expf(L[b*Ss + 256 + t]) * valid[b*Ss + 256 + t];
  float s = e0 + e1;
  #pragma unroll
  for (int o=32;o>0;o>>=1) s += __shfl_xor(s,o);
  if ((t&63)==0) wsum[t>>6] = s;
  __syncthreads();
  float tot = wsum[0]+wsum[1]+wsum[2]+wsum[3];
  out[b*Ss + t      ] = e0/tot;
  out[b*Ss + 256 + t] = e1/tot;
}

// ============================================================================
extern "C" void kernel_launch(void* const* d_in, const int* in_sizes, int n_in,
                              void* d_out, int out_size, void* d_ws, size_t ws_size,
                              hipStream_t stream)
{
  #define F(i) ((const float*)d_in[(i)])
  bool sig = (in_sizes[33] == 256);   // signature order vs dict order
  const float* d_eqW  = F(sig?35:33); const float* d_eqb  = F(sig?36:34);
  const float* d_ekW  = F(sig?37:35); const float* d_ekb  = F(sig?38:36);
  const float* d_evW  = F(sig?39:37); const float* d_evb  = F(sig?40:38);
  const float* d_eoW  = F(sig?41:39); const float* d_eob  = F(sig?42:40);
  const float* d_ln1g = F(sig?33:41); const float* d_ln1b = F(sig?34:42);

  // ---- workspace (~163 MiB) ----
  char* w = (char*)d_ws;
  bf16_t* P0 = (bf16_t*)w; w += (size_t)Mm*Hh*2;   // 32 MiB residual (enc)
  bf16_t* P1 = (bf16_t*)w; w += (size_t)Mm*Hh*2;   // 32 MiB residual (dec)
  bf16_t* H0 = (bf16_t*)w; w += (size_t)Mm*Hh*2;   // 32 MiB Q / AO / gelu
  bf16_t* H1 = (bf16_t*)w;                          // 32 MiB K / xs alias
  bf16_t* xs = (bf16_t*)w; w += (size_t)Mm*Hh*2;
  bf16_t* H2 = (bf16_t*)w;                          // 32 MiB VT / xt alias
  bf16_t* xt = (bf16_t*)w; w += (size_t)Mm*Hh*2;
  bf16_t* Wa = (bf16_t*)w; w += (size_t)(2*16384 + 16*65536)*2;  // 2.1 MiB
  float*  valid  = (float*)w; w += (size_t)Mm*4;
  float*  logits = (float*)w; w += (size_t)Mm*4;
  float* out = (float*)d_out;

  unsigned o_sem = 0, o_tem = 16384;
  unsigned o_w[16]; for (int i=0;i<16;i++) o_w[i] = 32768 + i*65536u;
  Prep18 pp;
  const float* srcs[18] = { F(5), F(7), F(9), F(11), F(13), F(15), F(19), F(21),
                            F(25), F(27), F(29), F(31), d_eqW, d_ekW, d_evW, d_eoW,
                            F(45), F(47) };
  unsigned offs[18] = { o_sem, o_tem, o_w[0],o_w[1],o_w[2],o_w[3],o_w[4],o_w[5],
                        o_w[6],o_w[7],o_w[8],o_w[9],o_w[10],o_w[11],o_w[12],o_w[13],
                        o_w[14],o_w[15] };
  for (int i=0;i<18;i++){ pp.d[i].s = srcs[i]; pp.d[i].off = offs[i]; pp.d[i].K = (i<2)?64:256; }

  dim3 blk(256);
  dim3 gLN(Mm/4);
  dim3 gG(Mm/64);
  dim3 gA(NHh, Bb, 4);
  dim3 gP(256, 18);
  const float* NF = nullptr; const bf16_t* NB = nullptr;

  k_prep<<<gP, blk, 0, stream>>>(pp, Wa);
  k_ln0<<<gLN, blk, 0, stream>>>(F(0), F(1),F(2), F(3),F(4), xs, xt, valid);

  k_gemm<0,0><<<gG, blk, 0, stream>>>(xs, Wa+o_sem, F(6), P0, NB,NF,NF,NF,NF, 64);
  k_gemm<0,0><<<gG, blk, 0, stream>>>(xt, Wa+o_tem, F(8), P1, NB,NF,NF,NF,NF, 64);

  // ---- encoder ----
  k_gemm<0,0><<<gG, blk, 0, stream>>>(P0, Wa+o_w[0], F(10), H0, NB,NF,NF,NF,NF, 256);
  k_gemm<0,0><<<gG, blk, 0, stream>>>(P0, Wa+o_w[1], F(12), H1, NB,NF,NF,NF,NF, 256);
  k_gemm<0,2><<<gG, blk, 0, stream>>>(P0, Wa+o_w[2], F(14), H2, NB,NF,NF,NF,NF, 256);
  k_attn<<<gA, blk, 0, stream>>>(H0, H1, H2, valid, H0);
  k_gemm<0,3><<<gG, blk, 0, stream>>>(H0, Wa+o_w[3], F(16), P0, P0, F(17),F(18), NF,NF, 256);
  k_gemm<1,0><<<gG, blk, 0, stream>>>(P0, Wa+o_w[4], F(20), H0, NB,NF,NF,NF,NF, 256);
  k_gemm<0,3><<<gG, blk, 0, stream>>>(H0, Wa+o_w[5], F(22), P0, P0, F(23),F(24), NF,NF, 256);

  // ---- decoder self-attention ----
  k_gemm<0,0><<<gG, blk, 0, stream>>>(P1, Wa+o_w[6], F(26), H0, NB,NF,NF,NF,NF, 256);
  k_gemm<0,0><<<gG, blk, 0, stream>>>(P1, Wa+o_w[7], F(28), H1, NB,NF,NF,NF,NF, 256);
  k_gemm<0,2><<<gG, blk, 0, stream>>>(P1, Wa+o_w[8], F(30), H2, NB,NF,NF,NF,NF, 256);
  k_attn<<<gA, blk, 0, stream>>>(H0, H1, H2, valid, H0);
  k_gemm<0,3><<<gG, blk, 0, stream>>>(H0, Wa+o_w[9], F(32), P1, P1, d_ln1g,d_ln1b, NF,NF, 256);

  // ---- decoder cross-attention ----
  k_gemm<0,0><<<gG, blk, 0, stream>>>(P1, Wa+o_w[10], d_eqb, H0, NB,NF,NF,NF,NF, 256);
  k_gemm<0,0><<<gG, blk, 0, stream>>>(P0, Wa+o_w[11], d_ekb, H1, NB,NF,NF,NF,NF, 256);
  k_gemm<0,2><<<gG, blk, 0, stream>>>(P0, Wa+o_w[12], d_evb, H2, NB,NF,NF,NF,NF, 256);
  k_attn<<<gA, blk, 0, stream>>>(H0, H1, H2, valid, H0);
  k_gemm<0,3><<<gG, blk, 0, stream>>>(H0, Wa+o_w[13], d_eob, P1, P1, F(43),F(44), NF,NF, 256);

  // ---- decoder FFN + fused ln3 + logits ----
  k_gemm<1,0><<<gG, blk, 0, stream>>>(P1, Wa+o_w[14], F(46), H0, NB,NF,NF,NF,NF, 256);
  k_gemm<0,5><<<gG, blk, 0, stream>>>(H0, Wa+o_w[15], F(48), logits, P1, F(49),F(50), F(51),F(52), 256);

  k_final<<<dim3(Bb), blk, 0, stream>>>(logits, valid, out);
  #undef F
}

// Round 10
// 1051.208 us; speedup vs baseline: 1.0508x; 1.0194x over previous
//
#include <hip/hip_runtime.h>
#include <hip/hip_bf16.h>

// ============================================================================
// TransformerChoiceNet forward. Round 10:
// (1) attention with TRUE 1-iter lookahead on K and V (r9 consumed K same-iter),
// (2) k_gemm __launch_bounds__(256,4) -> 4 blocks/CU (160 KiB LDS exact),
// (3) k_gemm3: merged independent GEMMs (QKV trios, emb pair) -> 17 dispatches.
// B=128 S=512 D=64 H=256 NH=8 HD=32, M=B*S=65536.
// ============================================================================

#define Bb  128
#define Ss  512
#define Hh  256
#define NHh 8
#define Mm  (Bb*Ss)

typedef unsigned short bf16_t;
typedef __attribute__((ext_vector_type(8))) short short8;
typedef __attribute__((ext_vector_type(4))) float f32x4;

__device__ __forceinline__ float bf2f(bf16_t h){
  union { unsigned int u; float f; } v; v.u = ((unsigned int)h)<<16; return v.f;
}
__device__ __forceinline__ bf16_t f2bf(float f){
  union { float f; unsigned int u; } v; v.f = f;
  unsigned int r = (v.u + 0x7fffu + ((v.u>>16)&1u)) >> 16;   // RNE
  return (bf16_t)r;
}
__device__ __forceinline__ unsigned pk_bf16(float a, float b){  // packed RNE cvt
  union { __hip_bfloat162 h; unsigned u; } v;
  v.h = __float22bfloat162_rn(float2{a,b});
  return v.u;
}
__device__ __forceinline__ short8 ld_bf8(const bf16_t* p){   // 16B load
  union { uint4 u; short8 s; } v; v.u = *(const uint4*)p; return v.s;
}
__device__ __forceinline__ void gload16(const bf16_t* g, bf16_t* l){
  __builtin_amdgcn_global_load_lds(
      (const __attribute__((address_space(1))) void*)g,
      (__attribute__((address_space(3))) void*)l, 16, 0, 0);
}
__device__ __forceinline__ float gelu_f(float x){
  float u = 0.7978845608028654f*(x + 0.044715f*x*x*x);
  return 0.5f*x*(1.0f + tanhf(u));
}

// ---------------- weight prep: fp32 W[k][n] -> bf16 Wt[n][k] ------------------
struct PrepDesc { const float* s; unsigned off; int K; };
struct Prep18  { PrepDesc d[18]; };

__global__ __launch_bounds__(256) void k_prep(Prep18 p, bf16_t* __restrict__ arena)
{
  PrepDesc dd = p.d[blockIdx.y];
  int i = blockIdx.x*256 + threadIdx.x;
  if (i < dd.K*256){
    int k = i>>8, n = i&255;
    arena[dd.off + n*dd.K + k] = f2bf(dd.s[i]);
  }
}

// ---------------- LN0 (two gains) + valid mask; bf16 out ----------------------
__global__ __launch_bounds__(256) void k_ln0(const float* __restrict__ src,
    const float* __restrict__ gs, const float* __restrict__ bs,
    const float* __restrict__ gt, const float* __restrict__ bt,
    bf16_t* __restrict__ xs, bf16_t* __restrict__ xt, float* __restrict__ valid)
{
  int row  = blockIdx.x*4 + (threadIdx.x>>6);
  int lane = threadIdx.x & 63;
  float x = src[(size_t)row*64 + lane];
  float s = x;
  #pragma unroll
  for (int o=32;o>0;o>>=1) s += __shfl_xor(s,o);
  float mean = s*(1.0f/64.0f);
  float d = x - mean;
  float ss = d*d;
  #pragma unroll
  for (int o=32;o>0;o>>=1) ss += __shfl_xor(ss,o);
  float r = rsqrtf(ss*(1.0f/64.0f) + 1e-5f);
  float xn = d*r;
  xs[(size_t)row*64+lane] = f2bf(xn*gs[lane] + bs[lane]);
  xt[(size_t)row*64+lane] = f2bf(xn*gt[lane] + bt[lane]);
  if (lane==0) valid[row] = (s != 0.0f) ? 1.0f : 0.0f;
}

// ---------------- merged independent GEMMs (QKV trio / emb pair) --------------
// blockIdx.y selects job. outm: 0 = bf16 C[M,256], 2 = bf16 VT[b][n][s].
struct GemmJob  { const bf16_t* A; const bf16_t* Wt; const float* bias; bf16_t* C; int outm; };
struct GemmJobs { GemmJob j[3]; };

__global__ __launch_bounds__(256,4) void k_gemm3(GemmJobs jobs, int K)
{
  __shared__ bf16_t As[8*512];    // 8 KB
  __shared__ bf16_t Bs[32*512];   // 32 KB
  GemmJob jb = jobs.j[blockIdx.y];
  int t = threadIdx.x, w = t>>6, lane = t&63, l15 = lane&15, quad = lane>>4;
  int m0 = blockIdx.x*64;
  f32x4 z = {0.f,0.f,0.f,0.f};
  f32x4 acc[4][4] = {{z,z,z,z},{z,z,z,z},{z,z,z,z},{z,z,z,z}};

  for (int k0=0; k0<K; k0+=64){
    #pragma unroll
    for (int j=0; j<2; j++){
      int id = 2*w + j; int kc32 = id>>2, mt = id&3;
      gload16(jb.A + (size_t)(m0 + mt*16 + l15)*K + k0 + kc32*32 + quad*8,
              &As[id*512]);
    }
    #pragma unroll
    for (int j=0; j<8; j++){
      int id = 8*w + j; int kc32 = id>>4, gnt = id&15;
      gload16(jb.Wt + (size_t)(gnt*16 + l15)*K + k0 + kc32*32 + quad*8,
              &Bs[id*512]);
    }
    __syncthreads();
    #pragma unroll
    for (int kc=0; kc<2; kc++){
      short8 a[4], b[4];
      #pragma unroll
      for (int mt=0; mt<4; mt++) a[mt] = ld_bf8(&As[(kc*4+mt)*512 + lane*8]);
      #pragma unroll
      for (int nt=0; nt<4; nt++) b[nt] = ld_bf8(&Bs[(kc*16 + w*4 + nt)*512 + lane*8]);
      #pragma unroll
      for (int mt=0; mt<4; mt++)
        #pragma unroll
        for (int nt=0; nt<4; nt++)
          acc[mt][nt] = __builtin_amdgcn_mfma_f32_16x16x32_bf16(a[mt], b[nt], acc[mt][nt], 0,0,0);
    }
    __syncthreads();
  }

  float bv[4];
  #pragma unroll
  for (int nt=0; nt<4; nt++) bv[nt] = jb.bias[w*64 + nt*16 + l15];

  if (jb.outm == 0){
    #pragma unroll
    for (int mt=0; mt<4; mt++)
      #pragma unroll
      for (int nt=0; nt<4; nt++){
        int m = m0 + mt*16 + quad*4;
        int col = w*64 + nt*16 + l15;
        #pragma unroll
        for (int r=0; r<4; r++)
          jb.C[(size_t)(m+r)*256 + col] = f2bf(acc[mt][nt][r] + bv[nt]);
      }
  } else {
    // VT[b][n][s]: 4 consecutive r = 4 consecutive s -> one 8B packed store
    #pragma unroll
    for (int mt=0; mt<4; mt++)
      #pragma unroll
      for (int nt=0; nt<4; nt++){
        int m = m0 + mt*16 + quad*4;
        int col = w*64 + nt*16 + l15;
        uint2 pk = { pk_bf16(acc[mt][nt][0]+bv[nt], acc[mt][nt][1]+bv[nt]),
                     pk_bf16(acc[mt][nt][2]+bv[nt], acc[mt][nt][3]+bv[nt]) };
        *(uint2*)&jb.C[((size_t)((m>>9)*256 + col))*512 + (m&511)] = pk;
      }
  }
}

// ---------------- MFMA GEMM with fused epilogues (single jobs) ----------------
// OUTM: 0 bf16 C[M,256] (EPI 0/1) | 3 LN(Pres+(acc+b)) -> bf16 P |
//       5 like 3 but dot outW -> fp32 logits.
template<int EPI, int OUTM>
__global__ __launch_bounds__(256,4) void k_gemm(const bf16_t* __restrict__ A,
    const bf16_t* __restrict__ Wt, const float* __restrict__ bias,
    void* __restrict__ Cv, const bf16_t* __restrict__ Pres,
    const float* __restrict__ g, const float* __restrict__ bb,
    const float* __restrict__ oW, const float* __restrict__ obp, int K)
{
  __shared__ bf16_t As[8*512];    // 8 KB
  __shared__ bf16_t Bs[32*512];   // 32 KB
  int t = threadIdx.x, w = t>>6, lane = t&63, l15 = lane&15, quad = lane>>4;
  int m0 = blockIdx.x*64;
  f32x4 z = {0.f,0.f,0.f,0.f};
  f32x4 acc[4][4] = {{z,z,z,z},{z,z,z,z},{z,z,z,z},{z,z,z,z}};

  for (int k0=0; k0<K; k0+=64){
    #pragma unroll
    for (int j=0; j<2; j++){
      int id = 2*w + j; int kc32 = id>>2, mt = id&3;
      gload16(A + (size_t)(m0 + mt*16 + l15)*K + k0 + kc32*32 + quad*8,
              &As[id*512]);
    }
    #pragma unroll
    for (int j=0; j<8; j++){
      int id = 8*w + j; int kc32 = id>>4, gnt = id&15;
      gload16(Wt + (size_t)(gnt*16 + l15)*K + k0 + kc32*32 + quad*8,
              &Bs[id*512]);
    }
    __syncthreads();
    #pragma unroll
    for (int kc=0; kc<2; kc++){
      short8 a[4], b[4];
      #pragma unroll
      for (int mt=0; mt<4; mt++) a[mt] = ld_bf8(&As[(kc*4+mt)*512 + lane*8]);
      #pragma unroll
      for (int nt=0; nt<4; nt++) b[nt] = ld_bf8(&Bs[(kc*16 + w*4 + nt)*512 + lane*8]);
      #pragma unroll
      for (int mt=0; mt<4; mt++)
        #pragma unroll
        for (int nt=0; nt<4; nt++)
          acc[mt][nt] = __builtin_amdgcn_mfma_f32_16x16x32_bf16(a[mt], b[nt], acc[mt][nt], 0,0,0);
    }
    __syncthreads();
  }

  float bv[4];
  #pragma unroll
  for (int nt=0; nt<4; nt++) bv[nt] = bias[w*64 + nt*16 + l15];

  if (OUTM==0){
    #pragma unroll
    for (int mt=0; mt<4; mt++)
      #pragma unroll
      for (int nt=0; nt<4; nt++)
        #pragma unroll
        for (int r=0; r<4; r++){
          int row = m0 + mt*16 + quad*4 + r;
          int col = w*64 + nt*16 + l15;
          float v = acc[mt][nt][r] + bv[nt];
          if (EPI==1) v = gelu_f(v);
          ((bf16_t*)Cv)[(size_t)row*256 + col] = f2bf(v);
        }
  } else {
    float* RedS = (float*)As;          // [64][4]
    float* RedQ = RedS + 256;          // [64][4]
    #pragma unroll
    for (int mt=0; mt<4; mt++)
      #pragma unroll
      for (int r=0; r<4; r++){
        int row = m0 + mt*16 + quad*4 + r;
        const bf16_t* pr = Pres + (size_t)row*256;
        float s = 0.f, q = 0.f;
        #pragma unroll
        for (int nt=0; nt<4; nt++){
          float v = acc[mt][nt][r] + bv[nt] + bf2f(pr[w*64 + nt*16 + l15]);
          s += v; q += v*v;
        }
        s += __shfl_xor(s,1); s += __shfl_xor(s,2);
        s += __shfl_xor(s,4); s += __shfl_xor(s,8);
        q += __shfl_xor(q,1); q += __shfl_xor(q,2);
        q += __shfl_xor(q,4); q += __shfl_xor(q,8);
        if (l15==0){
          int rr = mt*16 + quad*4 + r;
          RedS[rr*4 + w] = s; RedQ[rr*4 + w] = q;
        }
      }
    __syncthreads();

    float gv[4], bbv[4], wv[4];
    #pragma unroll
    for (int nt=0; nt<4; nt++){ gv[nt] = g[w*64+nt*16+l15]; bbv[nt] = bb[w*64+nt*16+l15]; }
    if (OUTM==5)
      #pragma unroll
      for (int nt=0; nt<4; nt++) wv[nt] = oW[w*64+nt*16+l15];

    float s2p[4][4];
    #pragma unroll
    for (int mt=0; mt<4; mt++)
      #pragma unroll
      for (int r=0; r<4; r++){
        int rr = mt*16 + quad*4 + r;
        int row = m0 + rr;
        float S = RedS[rr*4+0]+RedS[rr*4+1]+RedS[rr*4+2]+RedS[rr*4+3];
        float Q = RedQ[rr*4+0]+RedQ[rr*4+1]+RedQ[rr*4+2]+RedQ[rr*4+3];
        float mean = S*(1.0f/256.0f);
        float var  = Q*(1.0f/256.0f) - mean*mean;
        float rstd = rsqrtf(var + 1e-5f);
        const bf16_t* pr = Pres + (size_t)row*256;
        if (OUTM==3){
          bf16_t* po = (bf16_t*)Cv + (size_t)row*256;
          #pragma unroll
          for (int nt=0; nt<4; nt++){
            float v = acc[mt][nt][r] + bv[nt] + bf2f(pr[w*64 + nt*16 + l15]);
            po[w*64 + nt*16 + l15] = f2bf((v-mean)*rstd*gv[nt] + bbv[nt]);
          }
        } else {
          float s2 = 0.f;
          #pragma unroll
          for (int nt=0; nt<4; nt++){
            float v = acc[mt][nt][r] + bv[nt] + bf2f(pr[w*64 + nt*16 + l15]);
            s2 += ((v-mean)*rstd*gv[nt] + bbv[nt]) * wv[nt];
          }
          s2 += __shfl_xor(s2,1); s2 += __shfl_xor(s2,2);
          s2 += __shfl_xor(s2,4); s2 += __shfl_xor(s2,8);
          s2p[mt][r] = s2;
        }
      }
    if (OUTM==5){
      __syncthreads();
      #pragma unroll
      for (int mt=0; mt<4; mt++)
        #pragma unroll
        for (int r=0; r<4; r++)
          if (l15==0) RedS[(mt*16 + quad*4 + r)*4 + w] = s2p[mt][r];
      __syncthreads();
      if (w==0){
        float S = RedS[lane*4+0]+RedS[lane*4+1]+RedS[lane*4+2]+RedS[lane*4+3];
        ((float*)Cv)[m0 + lane] = S + obp[0];
      }
    }
  }
}

// ---------------- MFMA attention: 1-iter-lookahead pipeline -------------------
// Grid (h, b, qc). Wave = 2 q-tiles. K and V register-double-buffered: loads
// issued at iter kt2 are consumed at kt2+1 (full iteration of latency cover).
// S^T = mfma(aK,aQ): lane holds S[q=l15][key=ktile*16+quad*4+r].
__global__ __launch_bounds__(256) void k_attn(const bf16_t* __restrict__ Qm,
    const bf16_t* __restrict__ Km, const bf16_t* __restrict__ VT,
    const float* __restrict__ valid, bf16_t* __restrict__ AO)
{
  __shared__ bf16_t Pbuf[4][2][2][16][40];   // [wave][qtile][slot][q][key] 20 KB
  __shared__ float  Smask[512];              // 0 or -1e10
  int t = threadIdx.x, wave = t>>6, lane = t&63, l15 = lane&15, quad = lane>>4;
  int h = blockIdx.x, b = blockIdx.y, qc = blockIdx.z;
  int q0 = qc*128;
  const float scale = 0.17677669529663687f;   // 1/sqrt(32)

  Smask[t]     = (valid[b*Ss + t      ] != 0.f) ? 0.f : -1.0e10f;
  Smask[t+256] = (valid[b*Ss + t + 256] != 0.f) ? 0.f : -1.0e10f;
  __syncthreads();

  short8 aQ0 = ld_bf8(Qm + (size_t)(b*Ss + q0 + (wave*2  )*16 + l15)*256 + h*32 + quad*8);
  short8 aQ1 = ld_bf8(Qm + (size_t)(b*Ss + q0 + (wave*2+1)*16 + l15)*256 + h*32 + quad*8);
  const bf16_t* Kb = Km + (size_t)(b*Ss)*256 + h*32;          // + key*256
  const bf16_t* Vb = VT + ((size_t)b*256 + h*32)*512;         // + d*512 + key

  f32x4 z = {0.f,0.f,0.f,0.f};
  f32x4 O0[2] = {z,z}, O1[2] = {z,z};
  float ls0 = 0.f, ls1 = 0.f;

  // QK + exp + pack for tile kt2n into slot kt2n&1, from register K frags
  auto process = [&](int kt2n, short8 K0, short8 K1){
    int s = kt2n & 1;
    #pragma unroll
    for (int half=0; half<2; half++){
      short8 aK = half ? K1 : K0;
      int ktile = kt2n*2 + half;
      f32x4 s0 = __builtin_amdgcn_mfma_f32_16x16x32_bf16(aK, aQ0, z, 0,0,0);
      f32x4 s1 = __builtin_amdgcn_mfma_f32_16x16x32_bf16(aK, aQ1, z, 0,0,0);
      float4 mb = *(const float4*)&Smask[ktile*16 + quad*4];
      float p00 = __expf(fmaf(s0[0],scale, mb.x));
      float p01 = __expf(fmaf(s0[1],scale, mb.y));
      float p02 = __expf(fmaf(s0[2],scale, mb.z));
      float p03 = __expf(fmaf(s0[3],scale, mb.w));
      float p10 = __expf(fmaf(s1[0],scale, mb.x));
      float p11 = __expf(fmaf(s1[1],scale, mb.y));
      float p12 = __expf(fmaf(s1[2],scale, mb.z));
      float p13 = __expf(fmaf(s1[3],scale, mb.w));
      ls0 += (p00+p01)+(p02+p03);
      ls1 += (p10+p11)+(p12+p13);
      uint2 w0 = { pk_bf16(p00,p01), pk_bf16(p02,p03) };
      uint2 w1 = { pk_bf16(p10,p11), pk_bf16(p12,p13) };
      *(uint2*)&Pbuf[wave][0][s][l15][half*16 + quad*4] = w0;
      *(uint2*)&Pbuf[wave][1][s][l15][half*16 + quad*4] = w1;
    }
  };
  auto loadK = [&](int n, short8& K0, short8& K1){
    K0 = ld_bf8(Kb + (size_t)((n*2  )*16 + l15)*256 + quad*8);
    K1 = ld_bf8(Kb + (size_t)((n*2+1)*16 + l15)*256 + quad*8);
  };
  auto loadV = [&](int n, short8& V0, short8& V1){
    V0 = ld_bf8(Vb + (size_t)(l15   )*512 + n*32 + quad*8);
    V1 = ld_bf8(Vb + (size_t)(16+l15)*512 + n*32 + quad*8);
  };

  // prologue: tile 0 processed; K(1), V(0) in flight
  short8 cK0, cK1, pK0, pK1, cV0, cV1, nK0, nK1, nV0, nV1;
  loadK(0, cK0, cK1);
  process(0, cK0, cK1);          // first-iteration bubble only
  loadK(1, pK0, pK1);
  loadV(0, cV0, cV1);

  #pragma unroll 2
  for (int kt2=0; kt2<16; kt2++){
    if (kt2+2 < 16) loadK(kt2+2, nK0, nK1);   // consumed at iter kt2+1
    if (kt2+1 < 16) loadV(kt2+1, nV0, nV1);   // consumed at iter kt2+1
    int s = kt2 & 1;
    short8 aP0 = ld_bf8(&Pbuf[wave][0][s][l15][quad*8]);
    short8 aP1 = ld_bf8(&Pbuf[wave][1][s][l15][quad*8]);
    O0[0] = __builtin_amdgcn_mfma_f32_16x16x32_bf16(aP0, cV0, O0[0], 0,0,0);
    O0[1] = __builtin_amdgcn_mfma_f32_16x16x32_bf16(aP0, cV1, O0[1], 0,0,0);
    O1[0] = __builtin_amdgcn_mfma_f32_16x16x32_bf16(aP1, cV0, O1[0], 0,0,0);
    O1[1] = __builtin_amdgcn_mfma_f32_16x16x32_bf16(aP1, cV1, O1[1], 0,0,0);
    if (kt2+1 < 16) process(kt2+1, pK0, pK1); // pK loaded a full iter ago
    pK0 = nK0; pK1 = nK1;
    cV0 = nV0; cV1 = nV1;
  }

  ls0 += __shfl_xor(ls0,16); ls0 += __shfl_xor(ls0,32);
  ls1 += __shfl_xor(ls1,16); ls1 += __shfl_xor(ls1,32);
  float linv0 = (ls0 > 0.f) ? 1.0f/ls0 : 0.f;
  float linv1 = (ls1 > 0.f) ? 1.0f/ls1 : 0.f;
  float i0[4], i1[4];
  #pragma unroll
  for (int r=0; r<4; r++){
    i0[r] = __shfl(linv0, quad*4 + r);
    i1[r] = __shfl(linv1, quad*4 + r);
  }
  size_t r0 = (size_t)(b*Ss + q0 + (wave*2  )*16);
  size_t r1 = (size_t)(b*Ss + q0 + (wave*2+1)*16);
  #pragma unroll
  for (int nt=0; nt<2; nt++)
    #pragma unroll
    for (int r=0; r<4; r++){
      AO[(r0 + quad*4 + r)*256 + h*32 + nt*16 + l15] = f2bf(O0[nt][r]*i0[r]);
      AO[(r1 + quad*4 + r)*256 + h*32 + nt*16 + l15] = f2bf(O1[nt][r]*i1[r]);
    }
}

// ---------------- final: p = exp(logits)*valid, normalize per batch -----------
__global__ __launch_bounds__(256) void k_final(const float* __restrict__ L,
    const float* __restrict__ valid, float* __restrict__ out)
{
  __shared__ float wsum[4];
  int b = blockIdx.x, t = threadIdx.x;
  float e0 = __expf(L[b*Ss + t      ]) * valid[b*Ss + t      ];
  float e1 = __expf(L[b*Ss + 256 + t]) * valid[b*Ss + 256 + t];
  float s = e0 + e1;
  #pragma unroll
  for (int o=32;o>0;o>>=1) s += __shfl_xor(s,o);
  if ((t&63)==0) wsum[t>>6] = s;
  __syncthreads();
  float tot = wsum[0]+wsum[1]+wsum[2]+wsum[3];
  out[b*Ss + t      ] = e0/tot;
  out[b*Ss + 256 + t] = e1/tot;
}

// ============================================================================
extern "C" void kernel_launch(void* const* d_in, const int* in_sizes, int n_in,
                              void* d_out, int out_size, void* d_ws, size_t ws_size,
                              hipStream_t stream)
{
  #define F(i) ((const float*)d_in[(i)])
  bool sig = (in_sizes[33] == 256);   // signature order vs dict order
  const float* d_eqW  = F(sig?35:33); const float* d_eqb  = F(sig?36:34);
  const float* d_ekW  = F(sig?37:35); const float* d_ekb  = F(sig?38:36);
  const float* d_evW  = F(sig?39:37); const float* d_evb  = F(sig?40:38);
  const float* d_eoW  = F(sig?41:39); const float* d_eob  = F(sig?42:40);
  const float* d_ln1g = F(sig?33:41); const float* d_ln1b = F(sig?34:42);

  // ---- workspace (~163 MiB) ----
  char* w = (char*)d_ws;
  bf16_t* P0 = (bf16_t*)w; w += (size_t)Mm*Hh*2;   // 32 MiB residual (enc)
  bf16_t* P1 = (bf16_t*)w; w += (size_t)Mm*Hh*2;   // 32 MiB residual (dec)
  bf16_t* H0 = (bf16_t*)w; w += (size_t)Mm*Hh*2;   // 32 MiB Q / AO / gelu
  bf16_t* H1 = (bf16_t*)w;                          // 32 MiB K / xs alias
  bf16_t* xs = (bf16_t*)w; w += (size_t)Mm*Hh*2;
  bf16_t* H2 = (bf16_t*)w;                          // 32 MiB VT / xt alias
  bf16_t* xt = (bf16_t*)w; w += (size_t)Mm*Hh*2;
  bf16_t* Wa = (bf16_t*)w; w += (size_t)(2*16384 + 16*65536)*2;  // 2.1 MiB
  float*  valid  = (float*)w; w += (size_t)Mm*4;
  float*  logits = (float*)w; w += (size_t)Mm*4;
  float* out = (float*)d_out;

  unsigned o_sem = 0, o_tem = 16384;
  unsigned o_w[16]; for (int i=0;i<16;i++) o_w[i] = 32768 + i*65536u;
  Prep18 pp;
  const float* srcs[18] = { F(5), F(7), F(9), F(11), F(13), F(15), F(19), F(21),
                            F(25), F(27), F(29), F(31), d_eqW, d_ekW, d_evW, d_eoW,
                            F(45), F(47) };
  unsigned offs[18] = { o_sem, o_tem, o_w[0],o_w[1],o_w[2],o_w[3],o_w[4],o_w[5],
                        o_w[6],o_w[7],o_w[8],o_w[9],o_w[10],o_w[11],o_w[12],o_w[13],
                        o_w[14],o_w[15] };
  for (int i=0;i<18;i++){ pp.d[i].s = srcs[i]; pp.d[i].off = offs[i]; pp.d[i].K = (i<2)?64:256; }

  dim3 blk(256);
  dim3 gLN(Mm/4);
  dim3 gG(Mm/64);
  dim3 gA(NHh, Bb, 4);
  dim3 gP(256, 18);
  const float* NF = nullptr; const bf16_t* NB = nullptr;

  k_prep<<<gP, blk, 0, stream>>>(pp, Wa);
  k_ln0<<<gLN, blk, 0, stream>>>(F(0), F(1),F(2), F(3),F(4), xs, xt, valid);

  auto J = [](const bf16_t* A, const bf16_t* Wt, const float* bias, bf16_t* C, int outm){
    GemmJob j; j.A=A; j.Wt=Wt; j.bias=bias; j.C=C; j.outm=outm; return j;
  };

  // emb pair (independent)
  {
    GemmJobs js; js.j[0] = J(xs, Wa+o_sem, F(6), P0, 0);
    js.j[1] = J(xt, Wa+o_tem, F(8), P1, 0); js.j[2] = js.j[0];
    k_gemm3<<<dim3(Mm/64,2), blk, 0, stream>>>(js, 64);
  }

  // ---- encoder ----
  {
    GemmJobs js; js.j[0] = J(P0, Wa+o_w[0], F(10), H0, 0);
    js.j[1] = J(P0, Wa+o_w[1], F(12), H1, 0);
    js.j[2] = J(P0, Wa+o_w[2], F(14), H2, 2);
    k_gemm3<<<dim3(Mm/64,3), blk, 0, stream>>>(js, 256);
  }
  k_attn<<<gA, blk, 0, stream>>>(H0, H1, H2, valid, H0);
  k_gemm<0,3><<<gG, blk, 0, stream>>>(H0, Wa+o_w[3], F(16), P0, P0, F(17),F(18), NF,NF, 256);
  k_gemm<1,0><<<gG, blk, 0, stream>>>(P0, Wa+o_w[4], F(20), H0, NB,NF,NF,NF,NF, 256);
  k_gemm<0,3><<<gG, blk, 0, stream>>>(H0, Wa+o_w[5], F(22), P0, P0, F(23),F(24), NF,NF, 256);

  // ---- decoder self-attention ----
  {
    GemmJobs js; js.j[0] = J(P1, Wa+o_w[6], F(26), H0, 0);
    js.j[1] = J(P1, Wa+o_w[7], F(28), H1, 0);
    js.j[2] = J(P1, Wa+o_w[8], F(30), H2, 2);
    k_gemm3<<<dim3(Mm/64,3), blk, 0, stream>>>(js, 256);
  }
  k_attn<<<gA, blk, 0, stream>>>(H0, H1, H2, valid, H0);
  k_gemm<0,3><<<gG, blk, 0, stream>>>(H0, Wa+o_w[9], F(32), P1, P1, d_ln1g,d_ln1b, NF,NF, 256);

  // ---- decoder cross-attention (Q from P1; K,V from P0) ----
  {
    GemmJobs js; js.j[0] = J(P1, Wa+o_w[10], d_eqb, H0, 0);
    js.j[1] = J(P0, Wa+o_w[11], d_ekb, H1, 0);
    js.j[2] = J(P0, Wa+o_w[12], d_evb, H2, 2);
    k_gemm3<<<dim3(Mm/64,3), blk, 0, stream>>>(js, 256);
  }
  k_attn<<<gA, blk, 0, stream>>>(H0, H1, H2, valid, H0);
  k_gemm<0,3><<<gG, blk, 0, stream>>>(H0, Wa+o_w[13], d_eob, P1, P1, F(43),F(44), NF,NF, 256);

  // ---- decoder FFN + fused ln3 + logits ----
  k_gemm<1,0><<<gG, blk, 0, stream>>>(P1, Wa+o_w[14], F(46), H0, NB,NF,NF,NF,NF, 256);
  k_gemm<0,5><<<gG, blk, 0, stream>>>(H0, Wa+o_w[15], F(48), logits, P1, F(49),F(50), F(51),F(52), 256);

  k_final<<<dim3(Bb), blk, 0, stream>>>(logits, valid, out);
  #undef F
}